// Round 1
// baseline (137.463 us; speedup 1.0000x reference)
//
#include <hip/hip_runtime.h>

// GLRFast forward: out = patchs - sum_e edge_weights[e] * neighbor_e(patchs)
// Fixed problem: B=4, G=8, C=32, H=128, W=128 (fp32).
// DELTAS order: e0=(-1,0) up, e1=(0,-1) left, e2=(0,+1) right, e3=(+1,0) down.
// Replicate padding == clamped indices.
//
// Memory-bound: ideal HBM traffic 64 MiB patch read + 8 MiB weights + 64 MiB
// write = 136 MiB -> ~22 us at 6.3 TB/s. One thread per float4 of output.

#define GLR_H   128
#define GLR_W   128
#define GLR_HW  (GLR_H * GLR_W)   // 16384 floats per plane

__global__ __launch_bounds__(256) void glr_fwd_kernel(
    const float* __restrict__ patchs,   // [B*G*C, H, W] = 1024 planes
    const float* __restrict__ ew,       // [B*G, 4, H, W] = 32 groups x 4 planes
    float* __restrict__ out)            // same shape as patchs
{
    const int tid   = blockIdx.x * 256 + threadIdx.x;  // 0 .. 4194303
    const int w4    = tid & 31;          // vec4 index in row (W/4 = 32)
    const int h     = (tid >> 5) & 127;
    const int plane = tid >> 12;         // 0 .. 1023  (= (b*G+g)*C + c)
    const int bg    = plane >> 5;        // plane / C, C = 32

    const int w   = w4 << 2;
    const int off = (h << 7) + w;

    const float* __restrict__ P = patchs + (size_t)plane * GLR_HW;
    const float* __restrict__ E = ew + (size_t)bg * 4 * GLR_HW;

    // center + vertical neighbors: aligned float4
    const float4 c4 = *(const float4*)(P + off);
    const int hu = (h == 0)   ? 0   : h - 1;
    const int hd = (h == 127) ? 127 : h + 1;
    const float4 up4 = *(const float4*)(P + (hu << 7) + w);
    const float4 dn4 = *(const float4*)(P + (hd << 7) + w);

    // horizontal neighbors: shift center vector, patch the edges with scalars
    const float lf = (w4 == 0)  ? c4.x : P[off - 1];
    const float rg = (w4 == 31) ? c4.w : P[off + 4];

    // weights, e-major planes
    const float4 e0 = *(const float4*)(E + off);               // up
    const float4 e1 = *(const float4*)(E + GLR_HW + off);      // left
    const float4 e2 = *(const float4*)(E + 2 * GLR_HW + off);  // right
    const float4 e3 = *(const float4*)(E + 3 * GLR_HW + off);  // down

    float4 o;
    o.x = c4.x - (up4.x * e0.x + lf   * e1.x + c4.y * e2.x + dn4.x * e3.x);
    o.y = c4.y - (up4.y * e0.y + c4.x * e1.y + c4.z * e2.y + dn4.y * e3.y);
    o.z = c4.z - (up4.z * e0.z + c4.y * e1.z + c4.w * e2.z + dn4.z * e3.z);
    o.w = c4.w - (up4.w * e0.w + c4.z * e1.w + rg   * e2.w + dn4.w * e3.w);

    *(float4*)(out + (size_t)plane * GLR_HW + off) = o;
}

extern "C" void kernel_launch(void* const* d_in, const int* in_sizes, int n_in,
                              void* d_out, int out_size, void* d_ws, size_t ws_size,
                              hipStream_t stream) {
    const float* patchs = (const float*)d_in[0];  // [4,8,32,128,128]
    const float* ew     = (const float*)d_in[1];  // [4,8,4,128,128]
    // d_in[2] = node_degree, unused in forward
    float* out = (float*)d_out;                   // [4,8,32,128,128]

    // 16777216 elements / 4 per thread / 256 per block = 16384 blocks
    glr_fwd_kernel<<<16384, 256, 0, stream>>>(patchs, ew, out);
}

// Round 2
// 130.880 us; speedup vs baseline: 1.0503x; 1.0503x over previous
//
#include <hip/hip_runtime.h>

// GLRFast forward: out = patchs - sum_e edge_weights[e] * neighbor_e(patchs)
// Fixed problem: B=4, G=8, C=32, H=128, W=128 (fp32).
// DELTAS order: e0=(-1,0) up, e1=(0,-1) left, e2=(0,+1) right, e3=(+1,0) down.
// Replicate padding == clamped indices.
//
// R1 restructure: weights are channel-independent -> hold them in registers
// and loop over 8 channels per thread (4 cgroups x 8 = 32 channels).
// Left/right neighbors come from lane shuffles of the center float4 instead
// of scalar loads. vmem per 16B output: 9 -> ~4.5, with 8-deep channel ILP.
//
// Block = 256 threads = 32 w4-positions x 4 cgroups x 2 rows, one bg.
// Grid = 32 bg x 64 row-pairs = 2048 blocks.

#define GLR_HW 16384   // 128*128 floats per plane

__global__ __launch_bounds__(256) void glr_fwd_kernel(
    const float* __restrict__ patchs,   // [B*G*C, H, W] = 1024 planes
    const float* __restrict__ ew,       // [B*G, 4, H, W]
    float* __restrict__ out)
{
    const int t    = threadIdx.x;
    const int w4   = t & 31;           // vec4 index in row
    const int cg   = (t >> 5) & 3;     // channel group (8 channels each)
    const int hsub = t >> 7;           // 0/1: row within the block's pair

    const int bg = blockIdx.x >> 6;                  // 32 bg groups
    const int h  = ((blockIdx.x & 63) << 1) + hsub;  // 0..127

    const int w    = w4 << 2;
    const int off  = (h << 7) + w;
    const int hu   = (h == 0)   ? h : h - 1;
    const int hd   = (h == 127) ? h : h + 1;
    const int offu = (hu << 7) + w;
    const int offd = (hd << 7) + w;

    // weights: channel-independent, load once into registers
    const float* __restrict__ E = ew + (size_t)bg * 4 * GLR_HW + off;
    const float4 e0 = *(const float4*)(E);               // up
    const float4 e1 = *(const float4*)(E + GLR_HW);      // left
    const float4 e2 = *(const float4*)(E + 2 * GLR_HW);  // right
    const float4 e3 = *(const float4*)(E + 3 * GLR_HW);  // down

    const bool atL = (w4 == 0);
    const bool atR = (w4 == 31);

    const size_t planeBase = ((size_t)bg * 32 + (size_t)cg * 8) * GLR_HW;
    const float* __restrict__ P = patchs + planeBase;
    float*       __restrict__ O = out    + planeBase;

    #pragma unroll 4
    for (int c = 0; c < 8; ++c) {
        const float4 c4  = *(const float4*)(P + off);
        const float4 up4 = *(const float4*)(P + offu);
        const float4 dn4 = *(const float4*)(P + offd);

        // horizontal neighbors via lane shuffle (lanes are consecutive w4;
        // row/cgroup boundaries at lanes 0/31/32/63 are fixed by the clamps)
        float lf = __shfl_up(c4.w, 1);
        float rg = __shfl_down(c4.x, 1);
        if (atL) lf = c4.x;
        if (atR) rg = c4.w;

        float4 o;
        o.x = c4.x - (up4.x * e0.x + lf   * e1.x + c4.y * e2.x + dn4.x * e3.x);
        o.y = c4.y - (up4.y * e0.y + c4.x * e1.y + c4.z * e2.y + dn4.y * e3.y);
        o.z = c4.z - (up4.z * e0.z + c4.y * e1.z + c4.w * e2.z + dn4.z * e3.z);
        o.w = c4.w - (up4.w * e0.w + c4.z * e1.w + rg   * e2.w + dn4.w * e3.w);

        *(float4*)(O + off) = o;
        P += GLR_HW;
        O += GLR_HW;
    }
}

extern "C" void kernel_launch(void* const* d_in, const int* in_sizes, int n_in,
                              void* d_out, int out_size, void* d_ws, size_t ws_size,
                              hipStream_t stream) {
    const float* patchs = (const float*)d_in[0];  // [4,8,32,128,128]
    const float* ew     = (const float*)d_in[1];  // [4,8,4,128,128]
    // d_in[2] = node_degree, unused in forward
    float* out = (float*)d_out;

    glr_fwd_kernel<<<2048, 256, 0, stream>>>(patchs, ew, out);
}

// Round 3
// 125.799 us; speedup vs baseline: 1.0927x; 1.0404x over previous
//
#include <hip/hip_runtime.h>

// GLRFast forward: out = patchs - sum_e edge_weights[e] * neighbor_e(patchs)
// Fixed problem: B=4, G=8, C=32, H=128, W=128 (fp32).
// DELTAS order: e0=(-1,0) up, e1=(0,-1) left, e2=(0,+1) right, e3=(+1,0) down.
// Replicate padding == clamped indices.
//
// R2 restructure: rolling-window row streaming.
//   thread = (plane, w4, 8-row strip); rows r-1,r,r+1 live in registers,
//   each iteration prefetches row r+2 (one iter ahead of use) + 4 weight
//   rows (L1-hot: 8 channels per block share them), computes, stores.
//   6 independent loads in flight per iteration per wave.
// Grid: 2048 blocks x 256 threads = 8192 waves = full 32 waves/CU fill,
// 8x block oversubscription. __launch_bounds__(256,8) pins VGPR<=64 so
// occupancy stays at max.

#define GLR_HW 16384   // 128*128 floats per plane

__global__ __launch_bounds__(256, 8) void glr_fwd_kernel(
    const float* __restrict__ patchs,   // [B*G*C, H, W] = 1024 planes
    const float* __restrict__ ew,       // [B*G, 4, H, W]
    float* __restrict__ out)
{
    const int t  = threadIdx.x;
    const int w4 = t & 31;          // vec4 index in row
    const int cl = t >> 5;          // 0..7 channel within group

    // blockIdx = bg*64 + strip*4 + cgroup : same-bg blocks adjacent so
    // co-resident blocks share the bg's weight slab in L2.
    const int bg     = blockIdx.x >> 6;        // 0..31
    const int strip  = (blockIdx.x >> 2) & 15; // 0..15 -> rows [8s, 8s+8)
    const int cgroup = blockIdx.x & 3;         // 0..3

    const int c     = (cgroup << 3) + cl;      // 0..31
    const int plane = (bg << 5) + c;
    const int r0    = strip << 3;
    const int w     = w4 << 2;

    const float* __restrict__ P = patchs + (size_t)plane * GLR_HW + w;
    float*       __restrict__ O = out    + (size_t)plane * GLR_HW + w;
    const float* __restrict__ E = ew + (size_t)bg * 4 * GLR_HW + w;

    const bool atL = (w4 == 0);
    const bool atR = (w4 == 31);

    // rolling rows: up = r-1 (clamped), cur = r, dn = r+1
    const int rup = (r0 == 0) ? 0 : r0 - 1;
    float4 up  = *(const float4*)(P + (rup << 7));
    float4 cur = *(const float4*)(P + (r0 << 7));
    float4 dn  = *(const float4*)(P + ((r0 + 1) << 7));  // r0 <= 120 so valid

    #pragma unroll
    for (int i = 0; i < 8; ++i) {
        const int r   = r0 + i;
        const int ro  = r << 7;
        const int rn2 = (r + 2 > 127) ? 127 : r + 2;

        // prefetch next-next row (used next iteration via rotation)
        const float4 dn2 = *(const float4*)(P + (rn2 << 7));

        // weights for this row (channel-independent; L1-hot across the block)
        const float4 e0 = *(const float4*)(E + ro);               // up
        const float4 e1 = *(const float4*)(E + GLR_HW + ro);      // left
        const float4 e2 = *(const float4*)(E + 2 * GLR_HW + ro);  // right
        const float4 e3 = *(const float4*)(E + 3 * GLR_HW + ro);  // down

        // horizontal neighbors via lane shuffle; wave = 2 channels x 32 w4,
        // the channel boundary at lanes 31/32 is fixed by the edge clamps.
        float lf = __shfl_up(cur.w, 1);
        float rg = __shfl_down(cur.x, 1);
        if (atL) lf = cur.x;
        if (atR) rg = cur.w;

        float4 o;
        o.x = cur.x - (up.x * e0.x + lf    * e1.x + cur.y * e2.x + dn.x * e3.x);
        o.y = cur.y - (up.y * e0.y + cur.x * e1.y + cur.z * e2.y + dn.y * e3.y);
        o.z = cur.z - (up.z * e0.z + cur.y * e1.z + cur.w * e2.z + dn.z * e3.z);
        o.w = cur.w - (up.w * e0.w + cur.z * e1.w + rg    * e2.w + dn.w * e3.w);

        *(float4*)(O + ro) = o;

        up = cur; cur = dn; dn = dn2;
    }
}

extern "C" void kernel_launch(void* const* d_in, const int* in_sizes, int n_in,
                              void* d_out, int out_size, void* d_ws, size_t ws_size,
                              hipStream_t stream) {
    const float* patchs = (const float*)d_in[0];  // [4,8,32,128,128]
    const float* ew     = (const float*)d_in[1];  // [4,8,4,128,128]
    // d_in[2] = node_degree, unused in forward
    float* out = (float*)d_out;

    glr_fwd_kernel<<<2048, 256, 0, stream>>>(patchs, ew, out);
}

// Round 4
// 124.311 us; speedup vs baseline: 1.1058x; 1.0120x over previous
//
#include <hip/hip_runtime.h>

// GLRFast forward: out = patchs - sum_e edge_weights[e] * neighbor_e(patchs)
// Fixed problem: B=4, G=8, C=32, H=128, W=128 (fp32).
// DELTAS order: e0=(-1,0) up, e1=(0,-1) left, e2=(0,+1) right, e3=(+1,0) down.
// Replicate padding == clamped indices.
//
// R3: kernel is vmem-ISSUE-bound (R2: 50 vmem insts/thread, 64% of them
// weight loads re-fetching channel-shared data). Stage the block's 16 KB
// weight slab in LDS once (4 coalesced dwordx4/thread), read weights via
// ds_read_b128 on the parallel LDS pipe. vmem/thread: 50 -> 22.
// Output is write-once -> nontemporal stores (don't evict weights from L2).
//
// Block = 256 threads = 32 w4 x 8 channels; rolling 3-row register window
// over an 8-row strip. Grid = 32 bg x 16 strips x 4 cgroups = 2048 blocks,
// __launch_bounds__(256,8) -> 32 waves/CU, LDS 16KB*8 = 128KB <= 160KB.

#define GLR_HW 16384   // 128*128 floats per plane

typedef float fvec4 __attribute__((ext_vector_type(4)));

__global__ __launch_bounds__(256, 8) void glr_fwd_kernel(
    const float* __restrict__ patchs,   // [B*G*C, H, W] = 1024 planes
    const float* __restrict__ ew,       // [B*G, 4, H, W]
    float* __restrict__ out)
{
    __shared__ float4 sw[1024];  // [e:4][row i:8][w4:32] = 16 KB

    const int t  = threadIdx.x;
    const int w4 = t & 31;          // vec4 index in row
    const int cl = t >> 5;          // 0..7 channel within group

    const int bg     = blockIdx.x >> 6;        // 0..31
    const int strip  = (blockIdx.x >> 2) & 15; // rows [8s, 8s+8)
    const int cgroup = blockIdx.x & 3;         // 0..3

    const int r0 = strip << 3;
    const int w  = w4 << 2;

    // ---- stage weight slab: 4 planes x 8 rows x 128 floats ----
    {
        const float* __restrict__ EW = ew + (size_t)bg * 4 * GLR_HW;
        #pragma unroll
        for (int k = 0; k < 4; ++k) {
            const int j  = t + (k << 8);     // 0..1023
            const int e  = j >> 8;
            const int i  = (j >> 5) & 7;
            const int wq = j & 31;
            sw[j] = *(const float4*)(EW + e * GLR_HW + ((r0 + i) << 7) + (wq << 2));
        }
    }

    const int plane = (bg << 5) + (cgroup << 3) + cl;

    const float* __restrict__ P = patchs + (size_t)plane * GLR_HW + w;
    float*       __restrict__ O = out    + (size_t)plane * GLR_HW + w;

    const bool atL = (w4 == 0);
    const bool atR = (w4 == 31);

    // rolling rows: up = r-1 (clamped), cur = r, dn = r+1 (r0 <= 120)
    const int rup = (r0 == 0) ? 0 : r0 - 1;
    float4 up  = *(const float4*)(P + (rup << 7));
    float4 cur = *(const float4*)(P + (r0 << 7));
    float4 dn  = *(const float4*)(P + ((r0 + 1) << 7));

    __syncthreads();

    #pragma unroll
    for (int i = 0; i < 8; ++i) {
        const int r   = r0 + i;
        const int ro  = r << 7;
        const int rn2 = (r + 2 > 127) ? 127 : r + 2;

        // prefetch next-next patch row (used next iteration via rotation)
        const float4 dn2 = *(const float4*)(P + (rn2 << 7));

        // weights from LDS (lanes i and i+32 broadcast the same address)
        const int si = (i << 5) + w4;
        const float4 e0 = sw[si];
        const float4 e1 = sw[256 + si];
        const float4 e2 = sw[512 + si];
        const float4 e3 = sw[768 + si];

        // horizontal neighbors via lane shuffle; the channel boundary at
        // lanes 31/32 is fixed by the edge clamps.
        float lf = __shfl_up(cur.w, 1);
        float rg = __shfl_down(cur.x, 1);
        if (atL) lf = cur.x;
        if (atR) rg = cur.w;

        fvec4 o;
        o.x = cur.x - (up.x * e0.x + lf    * e1.x + cur.y * e2.x + dn.x * e3.x);
        o.y = cur.y - (up.y * e0.y + cur.x * e1.y + cur.z * e2.y + dn.y * e3.y);
        o.z = cur.z - (up.z * e0.z + cur.y * e1.z + cur.w * e2.z + dn.z * e3.z);
        o.w = cur.w - (up.w * e0.w + cur.z * e1.w + rg    * e2.w + dn.w * e3.w);

        __builtin_nontemporal_store(o, (fvec4*)(O + ro));

        up = cur; cur = dn; dn = dn2;
    }
}

extern "C" void kernel_launch(void* const* d_in, const int* in_sizes, int n_in,
                              void* d_out, int out_size, void* d_ws, size_t ws_size,
                              hipStream_t stream) {
    const float* patchs = (const float*)d_in[0];  // [4,8,32,128,128]
    const float* ew     = (const float*)d_in[1];  // [4,8,4,128,128]
    // d_in[2] = node_degree, unused in forward
    float* out = (float*)d_out;

    glr_fwd_kernel<<<2048, 256, 0, stream>>>(patchs, ew, out);
}

// Round 5
// 124.125 us; speedup vs baseline: 1.1075x; 1.0015x over previous
//
#include <hip/hip_runtime.h>

// GLRFast forward: out = patchs - sum_e edge_weights[e] * neighbor_e(patchs)
// Fixed problem: B=4, G=8, C=32, H=128, W=128 (fp32).
// DELTAS order: e0=(-1,0) up, e1=(0,-1) left, e2=(0,+1) right, e3=(+1,0) down.
// Replicate padding == clamped indices.
//
// R4: latency-bound, not issue-bound (R3 post-mortem). Kill the rolling
// window: each thread burst-issues its whole 10-row patch column (8-row
// strip + 2 halo rows) as independent dwordx4 loads + 4 weight-stage loads
// BEFORE any wait (~14 KB in flight per wave, one latency exposure per
// strip), then computes all 8 rows from registers. Weights via LDS (R3).
// ~70 VGPR -> __launch_bounds__(256,6): 24 waves/CU, 6x16KB = 96KB LDS.
//
// Block = 256 threads = 32 w4 x 8 channels. Grid = 32 bg x 16 strips x
// 4 cgroups = 2048 blocks.

#define GLR_HW 16384   // 128*128 floats per plane

typedef float fvec4 __attribute__((ext_vector_type(4)));

__global__ __launch_bounds__(256, 6) void glr_fwd_kernel(
    const float* __restrict__ patchs,   // [B*G*C, H, W] = 1024 planes
    const float* __restrict__ ew,       // [B*G, 4, H, W]
    float* __restrict__ out)
{
    __shared__ float4 sw[1024];  // [e:4][row i:8][w4:32] = 16 KB

    const int t  = threadIdx.x;
    const int w4 = t & 31;          // vec4 index in row
    const int cl = t >> 5;          // 0..7 channel within group

    const int bg     = blockIdx.x >> 6;        // 0..31
    const int strip  = (blockIdx.x >> 2) & 15; // rows [8s, 8s+8)
    const int cgroup = blockIdx.x & 3;         // 0..3

    const int r0 = strip << 3;
    const int w  = w4 << 2;

    // ---- issue ALL global loads back-to-back, then wait once ----

    // weight slab loads (into registers; LDS write after patch loads issue)
    const float* __restrict__ EW = ew + (size_t)bg * 4 * GLR_HW;
    float4 wstage[4];
    #pragma unroll
    for (int k = 0; k < 4; ++k) {
        const int j  = t + (k << 8);     // 0..1023
        const int e  = j >> 8;
        const int i  = (j >> 5) & 7;
        const int wq = j & 31;
        wstage[k] = *(const float4*)(EW + e * GLR_HW + ((r0 + i) << 7) + (wq << 2));
    }

    const int plane = (bg << 5) + (cgroup << 3) + cl;
    const float* __restrict__ P = patchs + (size_t)plane * GLR_HW + w;
    float*       __restrict__ O = out    + (size_t)plane * GLR_HW + w;

    // patch column: rows r0-1 .. r0+8, clamped -> reg[0..9]
    float4 reg[10];
    #pragma unroll
    for (int i = 0; i < 10; ++i) {
        int r = r0 + i - 1;
        r = (r < 0) ? 0 : (r > 127 ? 127 : r);
        reg[i] = *(const float4*)(P + (r << 7));
    }

    // stage weights to LDS
    #pragma unroll
    for (int k = 0; k < 4; ++k)
        sw[t + (k << 8)] = wstage[k];
    __syncthreads();

    const bool atL = (w4 == 0);
    const bool atR = (w4 == 31);

    // ---- compute 8 rows from registers (no loop-carried load deps) ----
    #pragma unroll
    for (int i = 0; i < 8; ++i) {
        const float4 up  = reg[i];
        const float4 cur = reg[i + 1];
        const float4 dn  = reg[i + 2];

        const int si = (i << 5) + w4;
        const float4 e0 = sw[si];
        const float4 e1 = sw[256 + si];
        const float4 e2 = sw[512 + si];
        const float4 e3 = sw[768 + si];

        // horizontal neighbors via lane shuffle; the channel boundary at
        // lanes 31/32 is fixed by the edge clamps.
        float lf = __shfl_up(cur.w, 1);
        float rg = __shfl_down(cur.x, 1);
        if (atL) lf = cur.x;
        if (atR) rg = cur.w;

        fvec4 o;
        o.x = cur.x - (up.x * e0.x + lf    * e1.x + cur.y * e2.x + dn.x * e3.x);
        o.y = cur.y - (up.y * e0.y + cur.x * e1.y + cur.z * e2.y + dn.y * e3.y);
        o.z = cur.z - (up.z * e0.z + cur.y * e1.z + cur.w * e2.z + dn.z * e3.z);
        o.w = cur.w - (up.w * e0.w + cur.z * e1.w + rg    * e2.w + dn.w * e3.w);

        __builtin_nontemporal_store(o, (fvec4*)(O + ((r0 + i) << 7)));
    }
}

extern "C" void kernel_launch(void* const* d_in, const int* in_sizes, int n_in,
                              void* d_out, int out_size, void* d_ws, size_t ws_size,
                              hipStream_t stream) {
    const float* patchs = (const float*)d_in[0];  // [4,8,32,128,128]
    const float* ew     = (const float*)d_in[1];  // [4,8,4,128,128]
    // d_in[2] = node_degree, unused in forward
    float* out = (float*)d_out;

    glr_fwd_kernel<<<2048, 256, 0, stream>>>(patchs, ew, out);
}

// Round 6
// 123.765 us; speedup vs baseline: 1.1107x; 1.0029x over previous
//
#include <hip/hip_runtime.h>

// GLRFast forward: out = patchs - sum_e edge_weights[e] * neighbor_e(patchs)
// Fixed problem: B=4, G=8, C=32, H=128, W=128 (fp32).
// DELTAS order: e0=(-1,0) up, e1=(0,-1) left, e2=(0,+1) right, e3=(+1,0) down.
// Replicate padding == clamped indices.
//
// R5: isolate two suspects from the ~36us plateau (floor ~22us):
//  (a) drop nontemporal stores (fill kernel hits 6.5 TB/s with NORMAL
//      stores; nt bypasses L2 and may write-combine worse),
//  (b) 16-row strips (was 8): patch halo over-fetch 25% -> 12.5% (-8 MB).
// Keep R4's burst structure: thread issues its whole 18-row patch column
// (16 + 2 halo) as independent dwordx4 loads before any wait (18 KB in
// flight per wave), weights staged once to a 32 KB LDS slab.
//
// Block = 256 threads = 32 w4 x 8 channels, 16-row strip of one bg.
// Grid = 32 bg x 8 strips x 4 cgroups = 1024 blocks.
// __launch_bounds__(256,4): VGPR cap 128 (reg[18]=72 + stage + addr),
// 16 waves/CU, LDS 32KB x 4 blocks = 128KB <= 160KB.

#define GLR_HW 16384   // 128*128 floats per plane

typedef float fvec4 __attribute__((ext_vector_type(4)));

__global__ __launch_bounds__(256, 4) void glr_fwd_kernel(
    const float* __restrict__ patchs,   // [B*G*C, H, W] = 1024 planes
    const float* __restrict__ ew,       // [B*G, 4, H, W]
    float* __restrict__ out)
{
    __shared__ float4 sw[2048];  // [e:4][row i:16][w4:32] = 32 KB

    const int t  = threadIdx.x;
    const int w4 = t & 31;          // vec4 index in row
    const int cl = t >> 5;          // 0..7 channel within group

    const int bg     = blockIdx.x >> 5;       // 0..31
    const int strip  = (blockIdx.x >> 2) & 7; // rows [16s, 16s+16)
    const int cgroup = blockIdx.x & 3;        // 0..3

    const int r0 = strip << 4;
    const int w  = w4 << 2;

    const int plane = (bg << 5) + (cgroup << 3) + cl;
    const float* __restrict__ P = patchs + (size_t)plane * GLR_HW + w;
    float*       __restrict__ O = out    + (size_t)plane * GLR_HW + w;

    // ---- burst-issue the whole 18-row patch column (independent loads) ----
    float4 reg[18];
    #pragma unroll
    for (int i = 0; i < 18; ++i) {
        int r = r0 + i - 1;
        r = (r < 0) ? 0 : (r > 127 ? 127 : r);
        reg[i] = *(const float4*)(P + (r << 7));
    }

    // ---- stage weight slab: 4 planes x 16 rows x 128 floats = 32 KB ----
    {
        const float* __restrict__ EW = ew + (size_t)bg * 4 * GLR_HW;
        #pragma unroll
        for (int k = 0; k < 8; ++k) {
            const int j  = t + (k << 8);     // 0..2047
            const int e  = j >> 9;
            const int i  = (j >> 5) & 15;
            const int wq = j & 31;
            sw[j] = *(const float4*)(EW + e * GLR_HW + ((r0 + i) << 7) + (wq << 2));
        }
    }
    __syncthreads();

    const bool atL = (w4 == 0);
    const bool atR = (w4 == 31);

    // ---- compute 16 rows from registers ----
    #pragma unroll
    for (int i = 0; i < 16; ++i) {
        const float4 up  = reg[i];
        const float4 cur = reg[i + 1];
        const float4 dn  = reg[i + 2];

        const int si = (i << 5) + w4;
        const float4 e0 = sw[si];
        const float4 e1 = sw[512 + si];
        const float4 e2 = sw[1024 + si];
        const float4 e3 = sw[1536 + si];

        // horizontal neighbors via lane shuffle; channel boundary at the
        // half-wave seam (lanes 31/32) is fixed by the edge clamps.
        float lf = __shfl_up(cur.w, 1);
        float rg = __shfl_down(cur.x, 1);
        if (atL) lf = cur.x;
        if (atR) rg = cur.w;

        fvec4 o;
        o.x = cur.x - (up.x * e0.x + lf    * e1.x + cur.y * e2.x + dn.x * e3.x);
        o.y = cur.y - (up.y * e0.y + cur.x * e1.y + cur.z * e2.y + dn.y * e3.y);
        o.z = cur.z - (up.z * e0.z + cur.y * e1.z + cur.w * e2.z + dn.z * e3.z);
        o.w = cur.w - (up.w * e0.w + cur.z * e1.w + rg    * e2.w + dn.w * e3.w);

        *(fvec4*)(O + ((r0 + i) << 7)) = o;   // normal store (no nt)
    }
}

extern "C" void kernel_launch(void* const* d_in, const int* in_sizes, int n_in,
                              void* d_out, int out_size, void* d_ws, size_t ws_size,
                              hipStream_t stream) {
    const float* patchs = (const float*)d_in[0];  // [4,8,32,128,128]
    const float* ew     = (const float*)d_in[1];  // [4,8,4,128,128]
    // d_in[2] = node_degree, unused in forward
    float* out = (float*)d_out;

    glr_fwd_kernel<<<1024, 256, 0, stream>>>(patchs, ew, out);
}